// Round 4
// baseline (284.406 us; speedup 1.0000x reference)
//
#include <hip/hip_runtime.h>
#include <hip/hip_bf16.h>
#include <math.h>

#define NK 256
#define NT 128
#define NC 32
#define ND 10
#define NSPK 1000000
#define LOG2PI 1.8378770664093453f
#define NCHUNK ((NSPK + 255) / 256)   // 3907 blocks, one 256-spike chunk each

#define FSTR 36            // dwords per LDS row (32 data + 4 pad), 144B = 16B-aligned
#define LDS_DW (256 * FSTR)           // 9216 dw = 36 KB, shared by feat & logits

typedef __attribute__((ext_vector_type(8))) short short8;
typedef __attribute__((ext_vector_type(4))) float floatx4;
typedef __attribute__((ext_vector_type(2))) float floatx2;
typedef __attribute__((ext_vector_type(4))) int intx4;

union FragCvt { intx4 i; short8 s; };

// ws layout:
//   [0,8)      double acc
//   [8,12)     uint counter
//   [64,320)   float cpack[64] : [c]=cst_c, [32+c]=w99_c
//   [1024,..)  int wt[64][32]  : bf16-pair-packed W, rows 0..31 hi, 32..63 lo
//   [16384,..) float pisT[NK*NT][32]

__device__ inline unsigned pack_bf16(float a, float b) {
  __hip_bfloat16 ha = __float2bfloat16(a), hb = __float2bfloat16(b);
  unsigned short ua, ub;
  __builtin_memcpy(&ua, &ha, 2);
  __builtin_memcpy(&ub, &hb, 2);
  return (unsigned)ua | ((unsigned)ub << 16);
}

// ============================ PREP (unchanged) =============================
__global__ void prep_kernel(const float* __restrict__ y,
                            const float* __restrict__ means,
                            const float* __restrict__ covs,
                            const float* __restrict__ b_mu,
                            const float* __restrict__ b_ls,
                            const float* __restrict__ beta_mu,
                            const float* __restrict__ beta_ls,
                            int* __restrict__ wt,
                            float* __restrict__ cpack,
                            float* __restrict__ pisT,
                            double* __restrict__ acc,
                            unsigned int* __restrict__ counter) {
  int blk = blockIdx.x;
  int tid = threadIdx.x;

  if (blk == 0) {
    int c = tid;
    if (c >= NC) return;

    float M[ND][ND];
    #pragma unroll
    for (int i = 0; i < ND; ++i)
      #pragma unroll
      for (int j = 0; j < ND; ++j)
        M[i][j] = covs[c * ND * ND + i * ND + j];

    // Cholesky, lower triangle in place
    float logdet = 0.f;
    #pragma unroll
    for (int j = 0; j < ND; ++j) {
      float d = M[j][j];
      #pragma unroll
      for (int k = 0; k < ND; ++k) if (k < j) d -= M[j][k] * M[j][k];
      float sq = sqrtf(d);
      M[j][j] = sq;
      logdet += 2.f * __logf(sq);
      float inv = 1.f / sq;
      #pragma unroll
      for (int i = 0; i < ND; ++i) {
        if (i > j) {
          float s2 = M[i][j];
          #pragma unroll
          for (int k = 0; k < ND; ++k) if (k < j) s2 -= M[i][k] * M[j][k];
          M[i][j] = s2 * inv;
        }
      }
    }

    // invert lower triangle in place: M(lower) := L^-1
    #pragma unroll
    for (int j = 0; j < ND; ++j) {
      M[j][j] = 1.f / M[j][j];
      #pragma unroll
      for (int i = 0; i < ND; ++i) {
        if (i > j) {
          float s2 = 0.f;
          #pragma unroll
          for (int k = 0; k < ND; ++k) if (k >= j && k < i) s2 += M[i][k] * M[k][j];
          M[i][j] = -s2 / M[i][i];
        }
      }
    }

    // P = Li^T Li : off-diag -> upper triangle of M, diag -> pd[]
    float pd[ND];
    #pragma unroll
    for (int i = 0; i < ND; ++i) {
      #pragma unroll
      for (int jj = 0; jj < ND; ++jj) {
        if (jj >= i) {
          float s2 = 0.f;
          #pragma unroll
          for (int k = 0; k < ND; ++k) if (k >= jj) s2 += M[k][i] * M[k][jj];
          if (jj > i) M[i][jj] = s2;
          else pd[i] = s2;
        }
      }
    }

    float mu[ND], q[ND];
    #pragma unroll
    for (int i = 0; i < ND; ++i) mu[i] = means[c * ND + i];
    float muPmu = 0.f;
    #pragma unroll
    for (int i = 0; i < ND; ++i) {
      float a2 = pd[i] * mu[i];
      #pragma unroll
      for (int j = 0; j < ND; ++j) {
        if (j < i) a2 += M[j][i] * mu[j];
        if (j > i) a2 += M[i][j] * mu[j];
      }
      q[i] = a2;
      muPmu += mu[i] * a2;
    }
    float cst = -0.5f * ((float)ND * LOG2PI + logdet + muPmu);

    float wv[64];
    int p = 0;
    #pragma unroll
    for (int i = 0; i < ND; ++i)
      #pragma unroll
      for (int j = 0; j < ND; ++j)
        if (j >= i && !(i == 9 && j == 9))
          wv[p++] = (i == j) ? -0.5f * pd[i] : -M[i][j];
    #pragma unroll
    for (int i = 0; i < ND; ++i) wv[54 + i] = q[i];

    #pragma unroll
    for (int j = 0; j < 32; ++j) {
      float a = wv[2 * j], b = wv[2 * j + 1];
      float ah = __bfloat162float(__float2bfloat16(a));
      float bh = __bfloat162float(__float2bfloat16(b));
      wt[c * 32 + j] = (int)pack_bf16(ah, bh);
      wt[(32 + c) * 32 + j] = (int)pack_bf16(a - ah, b - bh);
    }
    cpack[c] = cst;
    cpack[32 + c] = -0.5f * pd[9];   // w99

  } else if (blk == 1) {
    float local = 0.f;
    for (int i = tid; i < NC; i += 256)
      local += fmaf(-0.5f * b_mu[i], b_mu[i], b_ls[i]);
    for (int i = tid; i < NC * NT; i += 256)
      local += fmaf(-0.5f * beta_mu[i], beta_mu[i], beta_ls[i]);
    #pragma unroll
    for (int off = 32; off > 0; off >>= 1) local += __shfl_down(local, off);
    __shared__ float red[4];
    if ((tid & 63) == 0) red[tid >> 6] = local;
    __syncthreads();
    if (tid == 0) {
      acc[0] = (double)(red[0] + red[1] + red[2] + red[3]);
      counter[0] = 0u;
    }

  } else {
    int id = (blk - 2) * 256 + tid;          // id = k*NT + t
    int t = id & (NT - 1);
    float yv = y[id];
    float v[NC];
    float m = -1e30f;
    #pragma unroll
    for (int c = 0; c < NC; ++c) {
      v[c] = fmaf(beta_mu[c * NT + t], yv, b_mu[c]);
      m = fmaxf(m, v[c]);
    }
    float ssum = 0.f;
    #pragma unroll
    for (int c = 0; c < NC; ++c) ssum += __expf(v[c] - m);
    float lz = m + __logf(ssum);
    float* outp = pisT + (size_t)id * NC;
    #pragma unroll
    for (int c = 0; c < NC; ++c) outp[c] = v[c] - lz;
  }
}

// ======= MAIN: one chunk per block (3907 blocks), HW-backfilled ============
// Non-persistent: each block handles exactly one 256-spike chunk. The HW
// dispatcher backfills CUs as blocks retire, keeping residency pinned at the
// 4-blocks/CU LDS cap for the whole run (vs ~26% time-avg occupancy of the
// persistent version). Barrier-free: each wave owns a private 64-row LDS slab
// (writes feat rows [wv*64,wv*64+64), reads frags from them, scatters logits
// back, epilogue reads row tid) -- no cross-wave LDS sharing, and same-wave
// cross-lane DS ordering is guaranteed by the in-order per-wave DS pipe.
__global__ __launch_bounds__(256, 4)
void spike_kernel(const float* __restrict__ s,
                  const int* __restrict__ ks,
                  const int* __restrict__ ts,
                  const int* __restrict__ wt,
                  const float* __restrict__ cpack,
                  const float* __restrict__ pisT,
                  double* __restrict__ acc,
                  unsigned int* __restrict__ counter,
                  float* __restrict__ out) {
  __shared__ int lds[LDS_DW];        // 36 KB: feat (stride 36), then logits
  __shared__ float red[4];

  int tid = threadIdx.x;
  int wv_ = tid >> 6, L = tid & 63;
  int r = L & 15, q = L >> 4;

  int n = blockIdx.x * 256 + tid;
  int nc = n < NSPK ? n : (NSPK - 1);

  // ---- issue ks/ts first (gather addr dep), then s row, then B-frags ------
  int kk = __builtin_nontemporal_load(ks + nc);
  int tt = __builtin_nontemporal_load(ts + nc);
  const float* srow = s + (size_t)nc * ND;
  floatx4 sA = __builtin_nontemporal_load((const floatx4*)srow);
  floatx4 sB = __builtin_nontemporal_load((const floatx4*)(srow + 4));
  floatx2 sC = __builtin_nontemporal_load((const floatx2*)(srow + 8));

  // B-frags (W hi+lo) from global -> registers (8 KB table, L1/L2-hot)
  FragCvt bf[2][2][2];   // [h][nt][kstep]
  #pragma unroll
  for (int h = 0; h < 2; ++h)
    #pragma unroll
    for (int nt = 0; nt < 2; ++nt)
      #pragma unroll
      for (int k2 = 0; k2 < 2; ++k2)
        bf[h][nt][k2].i =
            *(const intx4*)&wt[(h * 32 + nt * 16 + r) * 32 + k2 * 16 + q * 4];

  // ---- pisT gather as soon as kk/tt land (covered by feat+MFMA+scatter) ---
  const float4* lpp = (const float4*)(pisT + (size_t)(kk * NT + tt) * NC);
  float4 lpv[8];
  #pragma unroll
  for (int i = 0; i < 8; ++i) lpv[i] = lpp[i];

  float sv[10] = {sA.x, sA.y, sA.z, sA.w, sB.x, sB.y, sB.z, sB.w, sC.x, sC.y};
  float s9sq = sv[9] * sv[9];

  // ---- features -> bf16 pack -> LDS (own wave slab, row tid) --------------
  float fv[64];
  {
    int p = 0;
    #pragma unroll
    for (int i = 0; i < ND; ++i)
      #pragma unroll
      for (int j = 0; j < ND; ++j)
        if (j >= i && !(i == 9 && j == 9)) fv[p++] = sv[i] * sv[j];
    #pragma unroll
    for (int i = 0; i < ND; ++i) fv[54 + i] = sv[i];
  }
  {
    int rb = tid * FSTR;
    #pragma unroll
    for (int ch = 0; ch < 8; ++ch) {
      intx4 v;
      v.x = (int)pack_bf16(fv[8 * ch + 0], fv[8 * ch + 1]);
      v.y = (int)pack_bf16(fv[8 * ch + 2], fv[8 * ch + 3]);
      v.z = (int)pack_bf16(fv[8 * ch + 4], fv[8 * ch + 5]);
      v.w = (int)pack_bf16(fv[8 * ch + 6], fv[8 * ch + 7]);
      *(intx4*)&lds[rb + ch * 4] = v;
    }
  }

  // ---- MFMA: D[spike][c] = F x (Whi + Wlo), reads own wave slab -----------
  floatx4 accf[4][2];
  #pragma unroll
  for (int mt = 0; mt < 4; ++mt)
    #pragma unroll
    for (int nt = 0; nt < 2; ++nt)
      accf[mt][nt] = (floatx4){0.f, 0.f, 0.f, 0.f};

  #pragma unroll
  for (int mt = 0; mt < 4; ++mt) {
    #pragma unroll
    for (int k2 = 0; k2 < 2; ++k2) {
      FragCvt a;
      a.i = *(const intx4*)&lds[(wv_ * 64 + mt * 16 + r) * FSTR + k2 * 16 + q * 4];
      #pragma unroll
      for (int nt = 0; nt < 2; ++nt) {
        accf[mt][nt] = __builtin_amdgcn_mfma_f32_16x16x32_bf16(
            a.s, bf[0][nt][k2].s, accf[mt][nt], 0, 0, 0);
        accf[mt][nt] = __builtin_amdgcn_mfma_f32_16x16x32_bf16(
            a.s, bf[1][nt][k2].s, accf[mt][nt], 0, 0, 0);
      }
    }
  }

  // ---- scatter C-frags to LDS logits[spike][c] (own wave slab) ------------
  // Safe without barrier: frag reads of slab rows precede these writes in
  // program order; DS pipe is in-order per wave.
  #pragma unroll
  for (int mt = 0; mt < 4; ++mt)
    #pragma unroll
    for (int nt = 0; nt < 2; ++nt)
      #pragma unroll
      for (int rr = 0; rr < 4; ++rr) {
        int srow_ = wv_ * 64 + mt * 16 + q * 4 + rr;
        lds[srow_ * FSTR + nt * 16 + r] = __float_as_int(accf[mt][nt][rr]);
      }

  // ---- epilogue: logits += lp + cst + w99*s9^2 ; logsumexp ----------------
  float lse = 0.f;
  {
    float lp[32];
    #pragma unroll
    for (int i = 0; i < 8; ++i) {
      lp[4 * i + 0] = lpv[i].x; lp[4 * i + 1] = lpv[i].y;
      lp[4 * i + 2] = lpv[i].z; lp[4 * i + 3] = lpv[i].w;
    }
    int base = tid * FSTR;
    float lg[32];
    #pragma unroll
    for (int g = 0; g < 8; ++g) {
      intx4 lv = *(const intx4*)&lds[base + g * 4];
      lg[4 * g + 0] = __int_as_float(lv.x);
      lg[4 * g + 1] = __int_as_float(lv.y);
      lg[4 * g + 2] = __int_as_float(lv.z);
      lg[4 * g + 3] = __int_as_float(lv.w);
    }
    #pragma unroll
    for (int c = 0; c < 32; ++c)
      lg[c] += lp[c] + fmaf(cpack[32 + c], s9sq, cpack[c]);

    // max via 5-level tree (exact; cuts 31-deep dependent chain to 5)
    float m16[16];
    #pragma unroll
    for (int c = 0; c < 16; ++c) m16[c] = fmaxf(lg[c], lg[c + 16]);
    float m8[8];
    #pragma unroll
    for (int c = 0; c < 8; ++c) m8[c] = fmaxf(m16[c], m16[c + 8]);
    float m4[4];
    #pragma unroll
    for (int c = 0; c < 4; ++c) m4[c] = fmaxf(m8[c], m8[c + 4]);
    float m = fmaxf(fmaxf(m4[0], m4[1]), fmaxf(m4[2], m4[3]));

    float ss0 = 0.f, ss1 = 0.f, ss2 = 0.f, ss3 = 0.f;
    #pragma unroll
    for (int c = 0; c < 8; ++c) {
      ss0 += __expf(lg[4 * c + 0] - m);
      ss1 += __expf(lg[4 * c + 1] - m);
      ss2 += __expf(lg[4 * c + 2] - m);
      ss3 += __expf(lg[4 * c + 3] - m);
    }
    float ssum = (ss0 + ss1) + (ss2 + ss3);
    if (n < NSPK) lse = m + __logf(ssum);
  }

  // block reduction -> one fp64 atomic per block
  #pragma unroll
  for (int off = 32; off > 0; off >>= 1) lse += __shfl_down(lse, off);
  if ((tid & 63) == 0) red[tid >> 6] = lse;
  __syncthreads();
  if (tid == 0) {
    atomicAdd(acc, (double)(red[0] + red[1] + red[2] + red[3]));
    __threadfence();
    unsigned int old = atomicAdd(counter, 1u);
    if (old == NCHUNK - 1) {
      __threadfence();
      double v = atomicAdd(acc, 0.0);
      out[0] = (float)v;
    }
  }
}

extern "C" void kernel_launch(void* const* d_in, const int* in_sizes, int n_in,
                              void* d_out, int out_size, void* d_ws, size_t ws_size,
                              hipStream_t stream) {
  const float* s       = (const float*)d_in[0];
  const float* y       = (const float*)d_in[1];
  const int*   ks      = (const int*)d_in[2];
  const int*   ts      = (const int*)d_in[3];
  const float* means   = (const float*)d_in[4];
  const float* covs    = (const float*)d_in[5];
  const float* b_mu    = (const float*)d_in[6];
  const float* b_ls    = (const float*)d_in[7];
  const float* beta_mu = (const float*)d_in[8];
  const float* beta_ls = (const float*)d_in[9];
  float* out = (float*)d_out;

  char* ws = (char*)d_ws;
  double* acc           = (double*)ws;
  unsigned int* counter = (unsigned int*)(ws + 8);
  float* cpack          = (float*)(ws + 64);
  int* wt               = (int*)(ws + 1024);
  float* pisT           = (float*)(ws + 16384);

  prep_kernel<<<2 + (NK * NT) / 256, 256, 0, stream>>>(
      y, means, covs, b_mu, b_ls, beta_mu, beta_ls, wt, cpack, pisT, acc, counter);
  spike_kernel<<<NCHUNK, 256, 0, stream>>>(
      s, ks, ts, wt, cpack, pisT, acc, counter, out);
}

// Round 5
// 167.344 us; speedup vs baseline: 1.6995x; 1.6995x over previous
//
#include <hip/hip_runtime.h>
#include <hip/hip_bf16.h>
#include <math.h>

#define NK 256
#define NT 128
#define NC 32
#define ND 10
#define NSPK 1000000
#define LOG2PI 1.8378770664093453f
#define NCHUNK ((NSPK + 255) / 256)   // 3907
#define GRID 1024                     // 4 blocks/CU x 256 CUs, all co-resident

#define FSTR 36            // dwords per LDS row (32 data + 4 pad), 144B = 16B-aligned
#define LDS_DW (256 * FSTR)           // 9216 dw = 36 KB, shared by feat & logits

typedef __attribute__((ext_vector_type(8))) short short8;
typedef __attribute__((ext_vector_type(4))) float floatx4;
typedef __attribute__((ext_vector_type(2))) float floatx2;
typedef __attribute__((ext_vector_type(4))) int intx4;

union FragCvt { intx4 i; short8 s; };

// ws layout:
//   [0,8)      double acc
//   [8,12)     uint counter
//   [64,320)   float cpack[64] : [c]=cst_c, [32+c]=w99_c
//   [1024,..)  int wt[64][32]  : bf16-pair-packed W, rows 0..31 hi, 32..63 lo
//   [16384,..) float pisT[NK*NT][32]

__device__ inline unsigned pack_bf16(float a, float b) {
  __hip_bfloat16 ha = __float2bfloat16(a), hb = __float2bfloat16(b);
  unsigned short ua, ub;
  __builtin_memcpy(&ua, &ha, 2);
  __builtin_memcpy(&ub, &hb, 2);
  return (unsigned)ua | ((unsigned)ub << 16);
}

// ============================ PREP =========================================
// amdgpu_waves_per_eu(1,4): block 0's Cholesky/inverse holds ~190 floats;
// default heuristic VGPR caps would spill it to scratch. Allow up to 512.
__global__ __attribute__((amdgpu_waves_per_eu(1, 4)))
void prep_kernel(const float* __restrict__ y,
                 const float* __restrict__ means,
                 const float* __restrict__ covs,
                 const float* __restrict__ b_mu,
                 const float* __restrict__ b_ls,
                 const float* __restrict__ beta_mu,
                 const float* __restrict__ beta_ls,
                 int* __restrict__ wt,
                 float* __restrict__ cpack,
                 float* __restrict__ pisT,
                 double* __restrict__ acc,
                 unsigned int* __restrict__ counter) {
  int blk = blockIdx.x;
  int tid = threadIdx.x;

  if (blk == 0) {
    int c = tid;
    if (c >= NC) return;

    float M[ND][ND];
    #pragma unroll
    for (int i = 0; i < ND; ++i)
      #pragma unroll
      for (int j = 0; j < ND; ++j)
        M[i][j] = covs[c * ND * ND + i * ND + j];

    // Cholesky, lower triangle in place
    float logdet = 0.f;
    #pragma unroll
    for (int j = 0; j < ND; ++j) {
      float d = M[j][j];
      #pragma unroll
      for (int k = 0; k < ND; ++k) if (k < j) d -= M[j][k] * M[j][k];
      float sq = sqrtf(d);
      M[j][j] = sq;
      logdet += 2.f * __logf(sq);
      float inv = 1.f / sq;
      #pragma unroll
      for (int i = 0; i < ND; ++i) {
        if (i > j) {
          float s2 = M[i][j];
          #pragma unroll
          for (int k = 0; k < ND; ++k) if (k < j) s2 -= M[i][k] * M[j][k];
          M[i][j] = s2 * inv;
        }
      }
    }

    // invert lower triangle in place: M(lower) := L^-1
    #pragma unroll
    for (int j = 0; j < ND; ++j) {
      M[j][j] = 1.f / M[j][j];
      #pragma unroll
      for (int i = 0; i < ND; ++i) {
        if (i > j) {
          float s2 = 0.f;
          #pragma unroll
          for (int k = 0; k < ND; ++k) if (k >= j && k < i) s2 += M[i][k] * M[k][j];
          M[i][j] = -s2 / M[i][i];
        }
      }
    }

    // P = Li^T Li : off-diag -> upper triangle of M, diag -> pd[]
    float pd[ND];
    #pragma unroll
    for (int i = 0; i < ND; ++i) {
      #pragma unroll
      for (int jj = 0; jj < ND; ++jj) {
        if (jj >= i) {
          float s2 = 0.f;
          #pragma unroll
          for (int k = 0; k < ND; ++k) if (k >= jj) s2 += M[k][i] * M[k][jj];
          if (jj > i) M[i][jj] = s2;
          else pd[i] = s2;
        }
      }
    }

    float mu[ND], q[ND];
    #pragma unroll
    for (int i = 0; i < ND; ++i) mu[i] = means[c * ND + i];
    float muPmu = 0.f;
    #pragma unroll
    for (int i = 0; i < ND; ++i) {
      float a2 = pd[i] * mu[i];
      #pragma unroll
      for (int j = 0; j < ND; ++j) {
        if (j < i) a2 += M[j][i] * mu[j];
        if (j > i) a2 += M[i][j] * mu[j];
      }
      q[i] = a2;
      muPmu += mu[i] * a2;
    }
    float cst = -0.5f * ((float)ND * LOG2PI + logdet + muPmu);

    float wv[64];
    int p = 0;
    #pragma unroll
    for (int i = 0; i < ND; ++i)
      #pragma unroll
      for (int j = 0; j < ND; ++j)
        if (j >= i && !(i == 9 && j == 9))
          wv[p++] = (i == j) ? -0.5f * pd[i] : -M[i][j];
    #pragma unroll
    for (int i = 0; i < ND; ++i) wv[54 + i] = q[i];

    #pragma unroll
    for (int j = 0; j < 32; ++j) {
      float a = wv[2 * j], b = wv[2 * j + 1];
      float ah = __bfloat162float(__float2bfloat16(a));
      float bh = __bfloat162float(__float2bfloat16(b));
      wt[c * 32 + j] = (int)pack_bf16(ah, bh);
      wt[(32 + c) * 32 + j] = (int)pack_bf16(a - ah, b - bh);
    }
    cpack[c] = cst;
    cpack[32 + c] = -0.5f * pd[9];   // w99

  } else if (blk == 1) {
    float local = 0.f;
    for (int i = tid; i < NC; i += 256)
      local += fmaf(-0.5f * b_mu[i], b_mu[i], b_ls[i]);
    for (int i = tid; i < NC * NT; i += 256)
      local += fmaf(-0.5f * beta_mu[i], beta_mu[i], beta_ls[i]);
    #pragma unroll
    for (int off = 32; off > 0; off >>= 1) local += __shfl_down(local, off);
    __shared__ float red[4];
    if ((tid & 63) == 0) red[tid >> 6] = local;
    __syncthreads();
    if (tid == 0) {
      acc[0] = (double)(red[0] + red[1] + red[2] + red[3]);
      counter[0] = 0u;
    }

  } else {
    int id = (blk - 2) * 256 + tid;          // id = k*NT + t
    int t = id & (NT - 1);
    float yv = y[id];
    float v[NC];
    float m = -1e30f;
    #pragma unroll
    for (int c = 0; c < NC; ++c) {
      v[c] = fmaf(beta_mu[c * NT + t], yv, b_mu[c]);
      m = fmaxf(m, v[c]);
    }
    float ssum = 0.f;
    #pragma unroll
    for (int c = 0; c < NC; ++c) ssum += __expf(v[c] - m);
    float lz = m + __logf(ssum);
    float* outp = pisT + (size_t)id * NC;
    #pragma unroll
    for (int c = 0; c < NC; ++c) outp[c] = v[c] - lz;
  }
}

// ============== MAIN: 4-wave blocks, barrier-free, VGPR=128 budget =========
// amdgpu_waves_per_eu(4,4): LDS (36 KB) caps blocks at 4/CU = 4 waves/EU, so
// pin the register budget to exactly that occupancy (512/4 = 128 VGPR).
// Previous rounds: the allocator targeted 8 waves/EU -> 64 VGPR -> the 8
// gather loads + 3 s-loads + LDS reads were serialized through a handful of
// reused destination registers (plus scratch spills) -> all memory-level
// parallelism lost -> 78 us with every pipe <20% busy.
// Barrier-free: each wave owns a private 64-row LDS slab; no cross-wave LDS
// sharing; same-wave cross-lane DS ordering via the in-order DS pipe.
__global__ __launch_bounds__(256) __attribute__((amdgpu_waves_per_eu(4, 4)))
void spike_kernel(const float* __restrict__ s,
                  const int* __restrict__ ks,
                  const int* __restrict__ ts,
                  const int* __restrict__ wt,
                  const float* __restrict__ cpack,
                  const float* __restrict__ pisT,
                  double* __restrict__ acc,
                  unsigned int* __restrict__ counter,
                  float* __restrict__ out) {
  __shared__ int lds[LDS_DW];        // 36 KB: feat (stride 36), then logits
  __shared__ float red[4];

  int tid = threadIdx.x;
  int wv_ = tid >> 6, L = tid & 63;
  int r = L & 15, q = L >> 4;

  // feature index tables: term p = (TJ<0) ? sv[TI] : sv[TI]*sv[TJ]
  // (upper triangle i<=j excluding (9,9), then 10 linear terms; same
  //  enumeration as prep's wv[] packing). All indices fold at compile time.
  static constexpr int TI[64] = {
    0,0,0,0,0,0,0,0,0,0,
    1,1,1,1,1,1,1,1,1,
    2,2,2,2,2,2,2,2,
    3,3,3,3,3,3,3,
    4,4,4,4,4,4,
    5,5,5,5,5,
    6,6,6,6,
    7,7,7,
    8,8,
    0,1,2,3,4,5,6,7,8,9};
  static constexpr int TJ[64] = {
    0,1,2,3,4,5,6,7,8,9,
    1,2,3,4,5,6,7,8,9,
    2,3,4,5,6,7,8,9,
    3,4,5,6,7,8,9,
    4,5,6,7,8,9,
    5,6,7,8,9,
    6,7,8,9,
    7,8,9,
    8,9,
    -1,-1,-1,-1,-1,-1,-1,-1,-1,-1};

  // B-frags (W hi+lo) from global -> registers, once per block
  FragCvt bf[2][2][2];   // [h][nt][kstep]
  #pragma unroll
  for (int h = 0; h < 2; ++h)
    #pragma unroll
    for (int nt = 0; nt < 2; ++nt)
      #pragma unroll
      for (int k2 = 0; k2 < 2; ++k2)
        bf[h][nt][k2].i =
            *(const intx4*)&wt[(h * 32 + nt * 16 + r) * 32 + k2 * 16 + q * 4];

  float lse_sum = 0.f;

  // ---- prefetch chunk 0 (non-temporal: s/ks/ts are stream-once; keep L2
  //      for the pisT gather table) -----------------------------------------
  int ci = blockIdx.x;
  floatx4 sA, sB; floatx2 sC; int kk, tt;
  {
    int n = ci * 256 + tid;
    int nc = n < NSPK ? n : (NSPK - 1);
    const float* srow = s + (size_t)nc * ND;
    sA = __builtin_nontemporal_load((const floatx4*)srow);
    sB = __builtin_nontemporal_load((const floatx4*)(srow + 4));
    sC = __builtin_nontemporal_load((const floatx2*)(srow + 8));
    kk = __builtin_nontemporal_load(ks + nc);
    tt = __builtin_nontemporal_load(ts + nc);
  }

  for (; ci < NCHUNK; ci += GRID) {
    int n = ci * 256 + tid;
    float sv[10] = {sA.x, sA.y, sA.z, sA.w, sB.x, sB.y, sB.z, sB.w, sC.x, sC.y};
    float s9sq = sv[9] * sv[9];

    // ---- issue pisT gather for THIS chunk first (max coverage) ------------
    const float4* lpp = (const float4*)(pisT + (size_t)(kk * NT + tt) * NC);
    float4 lpv[8];
    #pragma unroll
    for (int i = 0; i < 8; ++i) lpv[i] = lpp[i];

    // ---- register prefetch of NEXT chunk's s/ks/ts ------------------------
    int cn = ci + GRID;
    if (cn < NCHUNK) {
      int n2 = cn * 256 + tid;
      int nc2 = n2 < NSPK ? n2 : (NSPK - 1);
      const float* srow2 = s + (size_t)nc2 * ND;
      sA = __builtin_nontemporal_load((const floatx4*)srow2);
      sB = __builtin_nontemporal_load((const floatx4*)(srow2 + 4));
      sC = __builtin_nontemporal_load((const floatx2*)(srow2 + 8));
      kk = __builtin_nontemporal_load(ks + nc2);
      tt = __builtin_nontemporal_load(ts + nc2);
    }

    // ---- features fused into bf16 pack -> LDS (no fv[64] array) -----------
    {
      int rb = tid * FSTR;
      #pragma unroll
      for (int ch = 0; ch < 8; ++ch) {
        float t_[8];
        #pragma unroll
        for (int e = 0; e < 8; ++e) {
          int p = 8 * ch + e;
          t_[e] = (TJ[p] < 0) ? sv[TI[p]] : sv[TI[p]] * sv[TJ[p]];
        }
        intx4 v;
        v.x = (int)pack_bf16(t_[0], t_[1]);
        v.y = (int)pack_bf16(t_[2], t_[3]);
        v.z = (int)pack_bf16(t_[4], t_[5]);
        v.w = (int)pack_bf16(t_[6], t_[7]);
        *(intx4*)&lds[rb + ch * 4] = v;
      }
    }

    // ---- MFMA: D[spike][c] = F x (Whi + Wlo), reads own wave slab ---------
    floatx4 accf[4][2];
    #pragma unroll
    for (int mt = 0; mt < 4; ++mt)
      #pragma unroll
      for (int nt = 0; nt < 2; ++nt)
        accf[mt][nt] = (floatx4){0.f, 0.f, 0.f, 0.f};

    #pragma unroll
    for (int mt = 0; mt < 4; ++mt) {
      #pragma unroll
      for (int k2 = 0; k2 < 2; ++k2) {
        FragCvt a;
        a.i = *(const intx4*)&lds[(wv_ * 64 + mt * 16 + r) * FSTR + k2 * 16 + q * 4];
        #pragma unroll
        for (int nt = 0; nt < 2; ++nt) {
          accf[mt][nt] = __builtin_amdgcn_mfma_f32_16x16x32_bf16(
              a.s, bf[0][nt][k2].s, accf[mt][nt], 0, 0, 0);
          accf[mt][nt] = __builtin_amdgcn_mfma_f32_16x16x32_bf16(
              a.s, bf[1][nt][k2].s, accf[mt][nt], 0, 0, 0);
        }
      }
    }

    // ---- scatter C-frags to LDS logits[spike][c] (own wave slab) ----------
    // Safe without barrier: frag reads of slab rows precede these writes in
    // program order; DS pipe is in-order per wave.
    #pragma unroll
    for (int mt = 0; mt < 4; ++mt)
      #pragma unroll
      for (int nt = 0; nt < 2; ++nt)
        #pragma unroll
        for (int rr = 0; rr < 4; ++rr) {
          int srow_ = wv_ * 64 + mt * 16 + q * 4 + rr;
          lds[srow_ * FSTR + nt * 16 + r] = __float_as_int(accf[mt][nt][rr]);
        }

    // ---- epilogue: logits += lp + cst + w99*s9^2 ; logsumexp --------------
    // Reads row tid: written by same-wave lanes above (in-order DS pipe).
    {
      float lp[32];
      #pragma unroll
      for (int i = 0; i < 8; ++i) {
        lp[4 * i + 0] = lpv[i].x; lp[4 * i + 1] = lpv[i].y;
        lp[4 * i + 2] = lpv[i].z; lp[4 * i + 3] = lpv[i].w;
      }
      int base = tid * FSTR;
      float lg[32];
      #pragma unroll
      for (int g = 0; g < 8; ++g) {
        intx4 lv = *(const intx4*)&lds[base + g * 4];
        lg[4 * g + 0] = __int_as_float(lv.x);
        lg[4 * g + 1] = __int_as_float(lv.y);
        lg[4 * g + 2] = __int_as_float(lv.z);
        lg[4 * g + 3] = __int_as_float(lv.w);
      }
      #pragma unroll
      for (int c = 0; c < 32; ++c)
        lg[c] += lp[c] + fmaf(cpack[32 + c], s9sq, cpack[c]);

      // max via 5-level tree (exact; cuts 31-deep dependent chain to 5)
      float m16[16];
      #pragma unroll
      for (int c = 0; c < 16; ++c) m16[c] = fmaxf(lg[c], lg[c + 16]);
      float m8[8];
      #pragma unroll
      for (int c = 0; c < 8; ++c) m8[c] = fmaxf(m16[c], m16[c + 8]);
      float m4[4];
      #pragma unroll
      for (int c = 0; c < 4; ++c) m4[c] = fmaxf(m8[c], m8[c + 4]);
      float m = fmaxf(fmaxf(m4[0], m4[1]), fmaxf(m4[2], m4[3]));

      float ss0 = 0.f, ss1 = 0.f, ss2 = 0.f, ss3 = 0.f;
      #pragma unroll
      for (int c = 0; c < 8; ++c) {
        ss0 += __expf(lg[4 * c + 0] - m);
        ss1 += __expf(lg[4 * c + 1] - m);
        ss2 += __expf(lg[4 * c + 2] - m);
        ss3 += __expf(lg[4 * c + 3] - m);
      }
      float ssum = (ss0 + ss1) + (ss2 + ss3);
      if (n < NSPK) lse_sum += m + __logf(ssum);
    }
  }

  // block reduction -> one fp64 atomic per block
  #pragma unroll
  for (int off = 32; off > 0; off >>= 1) lse_sum += __shfl_down(lse_sum, off);
  if ((tid & 63) == 0) red[tid >> 6] = lse_sum;
  __syncthreads();
  if (tid == 0) {
    atomicAdd(acc, (double)(red[0] + red[1] + red[2] + red[3]));
    __threadfence();
    unsigned int old = atomicAdd(counter, 1u);
    if (old == GRID - 1) {
      __threadfence();
      double v = atomicAdd(acc, 0.0);
      out[0] = (float)v;
    }
  }
}

extern "C" void kernel_launch(void* const* d_in, const int* in_sizes, int n_in,
                              void* d_out, int out_size, void* d_ws, size_t ws_size,
                              hipStream_t stream) {
  const float* s       = (const float*)d_in[0];
  const float* y       = (const float*)d_in[1];
  const int*   ks      = (const int*)d_in[2];
  const int*   ts      = (const int*)d_in[3];
  const float* means   = (const float*)d_in[4];
  const float* covs    = (const float*)d_in[5];
  const float* b_mu    = (const float*)d_in[6];
  const float* b_ls    = (const float*)d_in[7];
  const float* beta_mu = (const float*)d_in[8];
  const float* beta_ls = (const float*)d_in[9];
  float* out = (float*)d_out;

  char* ws = (char*)d_ws;
  double* acc           = (double*)ws;
  unsigned int* counter = (unsigned int*)(ws + 8);
  float* cpack          = (float*)(ws + 64);
  int* wt               = (int*)(ws + 1024);
  float* pisT           = (float*)(ws + 16384);

  prep_kernel<<<2 + (NK * NT) / 256, 256, 0, stream>>>(
      y, means, covs, b_mu, b_ls, beta_mu, beta_ls, wt, cpack, pisT, acc, counter);
  spike_kernel<<<GRID, 256, 0, stream>>>(
      s, ks, ts, wt, cpack, pisT, acc, counter, out);
}

// Round 7
// 160.038 us; speedup vs baseline: 1.7771x; 1.0457x over previous
//
#include <hip/hip_runtime.h>
#include <hip/hip_bf16.h>
#include <math.h>

#define NK 256
#define NT 128
#define NC 32
#define ND 10
#define NSPK 1000000
#define LOG2PI 1.8378770664093453f
#define NCHUNK ((NSPK + 255) / 256)   // 3907
#define GRID 1024                     // 4 blocks/CU x 256 CUs, all co-resident

#define FSTR 36            // dwords per LDS row (32 data + 4 pad), 144B = 16B-aligned
#define LDS_DW (256 * FSTR)           // 9216 dw = 36 KB, shared by feat & logits

typedef __attribute__((ext_vector_type(8))) short short8;
typedef __attribute__((ext_vector_type(4))) float floatx4;
typedef __attribute__((ext_vector_type(2))) float floatx2;
typedef __attribute__((ext_vector_type(4))) int intx4;

union FragCvt { intx4 i; short8 s; };

// ws layout:
//   [0,8)        double acc
//   [8,12)       uint counter
//   [64,320)     float cpack[64] : [c]=cst_c + b_c, [32+c]=w99_c
//   [1024,9216)  int wt[64][32]  : bf16-pair-packed W, rows 0..31 hi, 32..63 lo
//   [12288,28672) float betaT[128][32] : transposed beta_mu (16 KB, L1-resident)
//   [32768,294912) float2 yz[NK*NT] : {y[k,t], lz[k,t]} packed (256 KB, L2-resident)

__device__ inline unsigned pack_bf16(float a, float b) {
  __hip_bfloat16 ha = __float2bfloat16(a), hb = __float2bfloat16(b);
  unsigned short ua, ub;
  __builtin_memcpy(&ua, &ha, 2);
  __builtin_memcpy(&ub, &hb, 2);
  return (unsigned)ua | ((unsigned)ub << 16);
}

// ============================ PREP =========================================
// No more 4 MB log-softmax table: blocks >=2 write only the packed {y, lz}
// pairs (256 KB total) after staging beta in LDS; block 2 also emits the
// 16 KB transposed betaT used by spike's epilogue.
__global__ __attribute__((amdgpu_waves_per_eu(1, 4)))
void prep_kernel(const float* __restrict__ y,
                 const float* __restrict__ means,
                 const float* __restrict__ covs,
                 const float* __restrict__ b_mu,
                 const float* __restrict__ b_ls,
                 const float* __restrict__ beta_mu,
                 const float* __restrict__ beta_ls,
                 int* __restrict__ wt,
                 float* __restrict__ cpack,
                 float* __restrict__ betaT,
                 float* __restrict__ yz,
                 double* __restrict__ acc,
                 unsigned int* __restrict__ counter) {
  int blk = blockIdx.x;
  int tid = threadIdx.x;

  if (blk == 0) {
    int c = tid;
    if (c >= NC) return;

    float M[ND][ND];
    #pragma unroll
    for (int i = 0; i < ND; ++i)
      #pragma unroll
      for (int j = 0; j < ND; ++j)
        M[i][j] = covs[c * ND * ND + i * ND + j];

    // Cholesky, lower triangle in place
    float logdet = 0.f;
    #pragma unroll
    for (int j = 0; j < ND; ++j) {
      float d = M[j][j];
      #pragma unroll
      for (int k = 0; k < ND; ++k) if (k < j) d -= M[j][k] * M[j][k];
      float sq = sqrtf(d);
      M[j][j] = sq;
      logdet += 2.f * __logf(sq);
      float inv = 1.f / sq;
      #pragma unroll
      for (int i = 0; i < ND; ++i) {
        if (i > j) {
          float s2 = M[i][j];
          #pragma unroll
          for (int k = 0; k < ND; ++k) if (k < j) s2 -= M[i][k] * M[j][k];
          M[i][j] = s2 * inv;
        }
      }
    }

    // invert lower triangle in place: M(lower) := L^-1
    #pragma unroll
    for (int j = 0; j < ND; ++j) {
      M[j][j] = 1.f / M[j][j];
      #pragma unroll
      for (int i = 0; i < ND; ++i) {
        if (i > j) {
          float s2 = 0.f;
          #pragma unroll
          for (int k = 0; k < ND; ++k) if (k >= j && k < i) s2 += M[i][k] * M[k][j];
          M[i][j] = -s2 / M[i][i];
        }
      }
    }

    // P = Li^T Li : off-diag -> upper triangle of M, diag -> pd[]
    float pd[ND];
    #pragma unroll
    for (int i = 0; i < ND; ++i) {
      #pragma unroll
      for (int jj = 0; jj < ND; ++jj) {
        if (jj >= i) {
          float s2 = 0.f;
          #pragma unroll
          for (int k = 0; k < ND; ++k) if (k >= jj) s2 += M[k][i] * M[k][jj];
          if (jj > i) M[i][jj] = s2;
          else pd[i] = s2;
        }
      }
    }

    float mu[ND], q[ND];
    #pragma unroll
    for (int i = 0; i < ND; ++i) mu[i] = means[c * ND + i];
    float muPmu = 0.f;
    #pragma unroll
    for (int i = 0; i < ND; ++i) {
      float a2 = pd[i] * mu[i];
      #pragma unroll
      for (int j = 0; j < ND; ++j) {
        if (j < i) a2 += M[j][i] * mu[j];
        if (j > i) a2 += M[i][j] * mu[j];
      }
      q[i] = a2;
      muPmu += mu[i] * a2;
    }
    float cst = -0.5f * ((float)ND * LOG2PI + logdet + muPmu);

    float wv[64];
    int p = 0;
    #pragma unroll
    for (int i = 0; i < ND; ++i)
      #pragma unroll
      for (int j = 0; j < ND; ++j)
        if (j >= i && !(i == 9 && j == 9))
          wv[p++] = (i == j) ? -0.5f * pd[i] : -M[i][j];
    #pragma unroll
    for (int i = 0; i < ND; ++i) wv[54 + i] = q[i];

    #pragma unroll
    for (int j = 0; j < 32; ++j) {
      float a = wv[2 * j], b = wv[2 * j + 1];
      float ah = __bfloat162float(__float2bfloat16(a));
      float bh = __bfloat162float(__float2bfloat16(b));
      wt[c * 32 + j] = (int)pack_bf16(ah, bh);
      wt[(32 + c) * 32 + j] = (int)pack_bf16(a - ah, b - bh);
    }
    cpack[c] = cst + b_mu[c];        // fold b_c into the per-component const
    cpack[32 + c] = -0.5f * pd[9];   // w99

  } else if (blk == 1) {
    float local = 0.f;
    for (int i = tid; i < NC; i += 256)
      local += fmaf(-0.5f * b_mu[i], b_mu[i], b_ls[i]);
    for (int i = tid; i < NC * NT; i += 256)
      local += fmaf(-0.5f * beta_mu[i], beta_mu[i], beta_ls[i]);
    #pragma unroll
    for (int off = 32; off > 0; off >>= 1) local += __shfl_down(local, off);
    __shared__ float red[4];
    if ((tid & 63) == 0) red[tid >> 6] = local;
    __syncthreads();
    if (tid == 0) {
      acc[0] = (double)(red[0] + red[1] + red[2] + red[3]);
      counter[0] = 0u;
    }

  } else {
    // ---- yz table: {y[k,t], lz[k,t]} ; beta staged in LDS -----------------
    __shared__ float bsh[NC * NT];   // 16 KB
    for (int i = tid; i < NC * NT; i += 256) bsh[i] = beta_mu[i];
    __syncthreads();

    int id = (blk - 2) * 256 + tid;          // id = k*NT + t
    int t = id & (NT - 1);
    float yv = y[id];
    float v[NC];
    float m = -1e30f;
    #pragma unroll
    for (int c = 0; c < NC; ++c) {
      v[c] = fmaf(bsh[c * NT + t], yv, b_mu[c]);
      m = fmaxf(m, v[c]);
    }
    float ssum = 0.f;
    #pragma unroll
    for (int c = 0; c < NC; ++c) ssum += __expf(v[c] - m);
    float lz = m + __logf(ssum);
    ((floatx2*)yz)[id] = (floatx2){yv, lz};

    if (blk == 2) {
      // transposed beta: betaT[t*32+c] = beta_mu[c*128+t]
      for (int i = tid; i < NC * NT; i += 256) {
        int tt2 = i >> 5, cc2 = i & 31;
        betaT[i] = bsh[cc2 * NT + tt2];
      }
    }
  }
}

// ============== MAIN: 4-wave blocks, barrier-free, no pisT gather ==========
// Identical structure to round 5 except the epilogue: the 128 B divergent
// gather from the 4 MB pisT table (L1-thrashing: 256 threads x 128 B = L1
// size) is replaced by one 8 B gather from the 256 KB yz table (L2-resident)
// plus 8 x dwordx4 from the 16 KB L1-resident betaT table and 32 fma.
// LSE_c(ll + b + beta*y - lz) = LSE_c(ll + b + beta*y) - lz.
__global__ __launch_bounds__(256) __attribute__((amdgpu_waves_per_eu(4, 4)))
void spike_kernel(const float* __restrict__ s,
                  const int* __restrict__ ks,
                  const int* __restrict__ ts,
                  const int* __restrict__ wt,
                  const float* __restrict__ cpack,
                  const float* __restrict__ betaT,
                  const float* __restrict__ yz,
                  double* __restrict__ acc,
                  unsigned int* __restrict__ counter,
                  float* __restrict__ out) {
  __shared__ int lds[LDS_DW];        // 36 KB: feat (stride 36), then logits
  __shared__ float red[4];

  int tid = threadIdx.x;
  int wv_ = tid >> 6, L = tid & 63;
  int r = L & 15, q = L >> 4;

  // feature index tables: term p = (TJ<0) ? sv[TI] : sv[TI]*sv[TJ]
  static constexpr int TI[64] = {
    0,0,0,0,0,0,0,0,0,0,
    1,1,1,1,1,1,1,1,1,
    2,2,2,2,2,2,2,2,
    3,3,3,3,3,3,3,
    4,4,4,4,4,4,
    5,5,5,5,5,
    6,6,6,6,
    7,7,7,
    8,8,
    0,1,2,3,4,5,6,7,8,9};
  static constexpr int TJ[64] = {
    0,1,2,3,4,5,6,7,8,9,
    1,2,3,4,5,6,7,8,9,
    2,3,4,5,6,7,8,9,
    3,4,5,6,7,8,9,
    4,5,6,7,8,9,
    5,6,7,8,9,
    6,7,8,9,
    7,8,9,
    8,9,
    -1,-1,-1,-1,-1,-1,-1,-1,-1,-1};

  // B-frags (W hi+lo) from global -> registers, once per block
  FragCvt bf[2][2][2];   // [h][nt][kstep]
  #pragma unroll
  for (int h = 0; h < 2; ++h)
    #pragma unroll
    for (int nt = 0; nt < 2; ++nt)
      #pragma unroll
      for (int k2 = 0; k2 < 2; ++k2)
        bf[h][nt][k2].i =
            *(const intx4*)&wt[(h * 32 + nt * 16 + r) * 32 + k2 * 16 + q * 4];

  float lse_sum = 0.f;

  // ---- prefetch chunk 0 (non-temporal: s/ks/ts are stream-once) -----------
  int ci = blockIdx.x;
  floatx4 sA, sB; floatx2 sC; int kk, tt;
  {
    int n = ci * 256 + tid;
    int nc = n < NSPK ? n : (NSPK - 1);
    const float* srow = s + (size_t)nc * ND;
    sA = __builtin_nontemporal_load((const floatx4*)srow);
    sB = __builtin_nontemporal_load((const floatx4*)(srow + 4));
    sC = __builtin_nontemporal_load((const floatx2*)(srow + 8));
    kk = __builtin_nontemporal_load(ks + nc);
    tt = __builtin_nontemporal_load(ts + nc);
  }

  for (; ci < NCHUNK; ci += GRID) {
    int n = ci * 256 + tid;
    float sv[10] = {sA.x, sA.y, sA.z, sA.w, sB.x, sB.y, sB.z, sB.w, sC.x, sC.y};
    float s9sq = sv[9] * sv[9];
    int myt = tt;   // keep this chunk's t before prefetch overwrites

    // ---- issue yz gather (8 B, L2-resident) for THIS chunk ----------------
    floatx2 yzv = ((const floatx2*)yz)[kk * NT + tt];

    // ---- register prefetch of NEXT chunk's s/ks/ts ------------------------
    int cn = ci + GRID;
    if (cn < NCHUNK) {
      int n2 = cn * 256 + tid;
      int nc2 = n2 < NSPK ? n2 : (NSPK - 1);
      const float* srow2 = s + (size_t)nc2 * ND;
      sA = __builtin_nontemporal_load((const floatx4*)srow2);
      sB = __builtin_nontemporal_load((const floatx4*)(srow2 + 4));
      sC = __builtin_nontemporal_load((const floatx2*)(srow2 + 8));
      kk = __builtin_nontemporal_load(ks + nc2);
      tt = __builtin_nontemporal_load(ts + nc2);
    }

    // ---- features fused into bf16 pack -> LDS (own wave slab) -------------
    {
      int rb = tid * FSTR;
      #pragma unroll
      for (int ch = 0; ch < 8; ++ch) {
        float t_[8];
        #pragma unroll
        for (int e = 0; e < 8; ++e) {
          int p = 8 * ch + e;
          t_[e] = (TJ[p] < 0) ? sv[TI[p]] : sv[TI[p]] * sv[TJ[p]];
        }
        intx4 v;
        v.x = (int)pack_bf16(t_[0], t_[1]);
        v.y = (int)pack_bf16(t_[2], t_[3]);
        v.z = (int)pack_bf16(t_[4], t_[5]);
        v.w = (int)pack_bf16(t_[6], t_[7]);
        *(intx4*)&lds[rb + ch * 4] = v;
      }
    }

    // ---- MFMA: D[spike][c] = F x (Whi + Wlo), reads own wave slab ---------
    floatx4 accf[4][2];
    #pragma unroll
    for (int mt = 0; mt < 4; ++mt)
      #pragma unroll
      for (int nt = 0; nt < 2; ++nt)
        accf[mt][nt] = (floatx4){0.f, 0.f, 0.f, 0.f};

    #pragma unroll
    for (int mt = 0; mt < 4; ++mt) {
      #pragma unroll
      for (int k2 = 0; k2 < 2; ++k2) {
        FragCvt a;
        a.i = *(const intx4*)&lds[(wv_ * 64 + mt * 16 + r) * FSTR + k2 * 16 + q * 4];
        #pragma unroll
        for (int nt = 0; nt < 2; ++nt) {
          accf[mt][nt] = __builtin_amdgcn_mfma_f32_16x16x32_bf16(
              a.s, bf[0][nt][k2].s, accf[mt][nt], 0, 0, 0);
          accf[mt][nt] = __builtin_amdgcn_mfma_f32_16x16x32_bf16(
              a.s, bf[1][nt][k2].s, accf[mt][nt], 0, 0, 0);
        }
      }
    }

    // ---- scatter C-frags to LDS logits[spike][c] (own wave slab) ----------
    #pragma unroll
    for (int mt = 0; mt < 4; ++mt)
      #pragma unroll
      for (int nt = 0; nt < 2; ++nt)
        #pragma unroll
        for (int rr = 0; rr < 4; ++rr) {
          int srow_ = wv_ * 64 + mt * 16 + q * 4 + rr;
          lds[srow_ * FSTR + nt * 16 + r] = __float_as_int(accf[mt][nt][rr]);
        }

    // ---- epilogue: lg = FW + cst' + w99*s9^2 + beta[.,t]*y ; LSE - lz -----
    {
      int base = tid * FSTR;
      float lg[32];
      #pragma unroll
      for (int g = 0; g < 8; ++g) {
        intx4 lv = *(const intx4*)&lds[base + g * 4];
        lg[4 * g + 0] = __int_as_float(lv.x);
        lg[4 * g + 1] = __int_as_float(lv.y);
        lg[4 * g + 2] = __int_as_float(lv.z);
        lg[4 * g + 3] = __int_as_float(lv.w);
      }
      const float4* btp = (const float4*)(betaT + myt * NC);  // 128 B, L1-hot
      #pragma unroll
      for (int g = 0; g < 8; ++g) {
        float4 b4 = btp[g];
        lg[4 * g + 0] += fmaf(b4.x, yzv.x, fmaf(cpack[32 + 4*g+0], s9sq, cpack[4*g+0]));
        lg[4 * g + 1] += fmaf(b4.y, yzv.x, fmaf(cpack[32 + 4*g+1], s9sq, cpack[4*g+1]));
        lg[4 * g + 2] += fmaf(b4.z, yzv.x, fmaf(cpack[32 + 4*g+2], s9sq, cpack[4*g+2]));
        lg[4 * g + 3] += fmaf(b4.w, yzv.x, fmaf(cpack[32 + 4*g+3], s9sq, cpack[4*g+3]));
      }

      // max via 5-level tree (exact; cuts 31-deep dependent chain to 5)
      float m16[16];
      #pragma unroll
      for (int c = 0; c < 16; ++c) m16[c] = fmaxf(lg[c], lg[c + 16]);
      float m8[8];
      #pragma unroll
      for (int c = 0; c < 8; ++c) m8[c] = fmaxf(m16[c], m16[c + 8]);
      float m4[4];
      #pragma unroll
      for (int c = 0; c < 4; ++c) m4[c] = fmaxf(m8[c], m8[c + 4]);
      float m = fmaxf(fmaxf(m4[0], m4[1]), fmaxf(m4[2], m4[3]));

      float ss0 = 0.f, ss1 = 0.f, ss2 = 0.f, ss3 = 0.f;
      #pragma unroll
      for (int c = 0; c < 8; ++c) {
        ss0 += __expf(lg[4 * c + 0] - m);
        ss1 += __expf(lg[4 * c + 1] - m);
        ss2 += __expf(lg[4 * c + 2] - m);
        ss3 += __expf(lg[4 * c + 3] - m);
      }
      float ssum = (ss0 + ss1) + (ss2 + ss3);
      if (n < NSPK) lse_sum += m + __logf(ssum) - yzv.y;
    }
  }

  // block reduction -> one fp64 atomic per block
  #pragma unroll
  for (int off = 32; off > 0; off >>= 1) lse_sum += __shfl_down(lse_sum, off);
  if ((tid & 63) == 0) red[tid >> 6] = lse_sum;
  __syncthreads();
  if (tid == 0) {
    atomicAdd(acc, (double)(red[0] + red[1] + red[2] + red[3]));
    __threadfence();
    unsigned int old = atomicAdd(counter, 1u);
    if (old == GRID - 1) {
      __threadfence();
      double v = atomicAdd(acc, 0.0);
      out[0] = (float)v;
    }
  }
}

extern "C" void kernel_launch(void* const* d_in, const int* in_sizes, int n_in,
                              void* d_out, int out_size, void* d_ws, size_t ws_size,
                              hipStream_t stream) {
  const float* s       = (const float*)d_in[0];
  const float* y       = (const float*)d_in[1];
  const int*   ks      = (const int*)d_in[2];
  const int*   ts      = (const int*)d_in[3];
  const float* means   = (const float*)d_in[4];
  const float* covs    = (const float*)d_in[5];
  const float* b_mu    = (const float*)d_in[6];
  const float* b_ls    = (const float*)d_in[7];
  const float* beta_mu = (const float*)d_in[8];
  const float* beta_ls = (const float*)d_in[9];
  float* out = (float*)d_out;

  char* ws = (char*)d_ws;
  double* acc           = (double*)ws;
  unsigned int* counter = (unsigned int*)(ws + 8);
  float* cpack          = (float*)(ws + 64);
  int* wt               = (int*)(ws + 1024);
  float* betaT          = (float*)(ws + 12288);
  float* yz             = (float*)(ws + 32768);

  prep_kernel<<<2 + (NK * NT) / 256, 256, 0, stream>>>(
      y, means, covs, b_mu, b_ls, beta_mu, beta_ls, wt, cpack, betaT, yz, acc, counter);
  spike_kernel<<<GRID, 256, 0, stream>>>(
      s, ks, ts, wt, cpack, betaT, yz, acc, counter, out);
}

// Round 8
// 135.554 us; speedup vs baseline: 2.0981x; 1.1806x over previous
//
#include <hip/hip_runtime.h>
#include <hip/hip_bf16.h>
#include <math.h>

#define NK 256
#define NT 128
#define NC 32
#define ND 10
#define NSPK 1000000
#define LOG2PI 1.8378770664093453f
#define NCHUNK ((NSPK + 255) / 256)   // 3907
#define GRID 1024                     // 4 blocks/CU x 256 CUs, all co-resident

#define FSTR 36            // dwords per LDS row (32 data + 4 pad), 144B = 16B-aligned
#define LDS_DW (256 * FSTR)           // 9216 dw = 36 KB, shared by feat & logits

typedef __attribute__((ext_vector_type(8))) short short8;
typedef __attribute__((ext_vector_type(4))) float floatx4;
typedef __attribute__((ext_vector_type(2))) float floatx2;
typedef __attribute__((ext_vector_type(4))) int intx4;

union FragCvt { intx4 i; short8 s; };

// ws layout:
//   [0,8)        double acc            (prior-q scalar term, written by prep)
//   [8,12)       (unused)
//   [64,320)     float cpack[64] : [c]=cst_c + b_c, [32+c]=w99_c
//   [1024,9216)  int wt[64][32]  : bf16-pair-packed W, rows 0..31 hi, 32..63 lo
//   [12288,28672) float betaT[128][32] : transposed beta_mu (16 KB, L1-resident)
//   [32768,294912) float2 yz[NK*NT] : {y[k,t], lz[k,t]} packed (256 KB, L2-resident)
//   [294912,303104) double part[GRID] : per-block partials (plain stores, no atomics)

__device__ inline unsigned pack_bf16(float a, float b) {
  __hip_bfloat16 ha = __float2bfloat16(a), hb = __float2bfloat16(b);
  unsigned short ua, ub;
  __builtin_memcpy(&ua, &ha, 2);
  __builtin_memcpy(&ub, &hb, 2);
  return (unsigned)ua | ((unsigned)ub << 16);
}

// ============================ PREP =========================================
__global__ __attribute__((amdgpu_waves_per_eu(1, 4)))
void prep_kernel(const float* __restrict__ y,
                 const float* __restrict__ means,
                 const float* __restrict__ covs,
                 const float* __restrict__ b_mu,
                 const float* __restrict__ b_ls,
                 const float* __restrict__ beta_mu,
                 const float* __restrict__ beta_ls,
                 int* __restrict__ wt,
                 float* __restrict__ cpack,
                 float* __restrict__ betaT,
                 float* __restrict__ yz,
                 double* __restrict__ acc) {
  int blk = blockIdx.x;
  int tid = threadIdx.x;

  if (blk == 0) {
    int c = tid;
    if (c >= NC) return;

    float M[ND][ND];
    #pragma unroll
    for (int i = 0; i < ND; ++i)
      #pragma unroll
      for (int j = 0; j < ND; ++j)
        M[i][j] = covs[c * ND * ND + i * ND + j];

    // Cholesky, lower triangle in place
    float logdet = 0.f;
    #pragma unroll
    for (int j = 0; j < ND; ++j) {
      float d = M[j][j];
      #pragma unroll
      for (int k = 0; k < ND; ++k) if (k < j) d -= M[j][k] * M[j][k];
      float sq = sqrtf(d);
      M[j][j] = sq;
      logdet += 2.f * __logf(sq);
      float inv = 1.f / sq;
      #pragma unroll
      for (int i = 0; i < ND; ++i) {
        if (i > j) {
          float s2 = M[i][j];
          #pragma unroll
          for (int k = 0; k < ND; ++k) if (k < j) s2 -= M[i][k] * M[j][k];
          M[i][j] = s2 * inv;
        }
      }
    }

    // invert lower triangle in place: M(lower) := L^-1
    #pragma unroll
    for (int j = 0; j < ND; ++j) {
      M[j][j] = 1.f / M[j][j];
      #pragma unroll
      for (int i = 0; i < ND; ++i) {
        if (i > j) {
          float s2 = 0.f;
          #pragma unroll
          for (int k = 0; k < ND; ++k) if (k >= j && k < i) s2 += M[i][k] * M[k][j];
          M[i][j] = -s2 / M[i][i];
        }
      }
    }

    // P = Li^T Li : off-diag -> upper triangle of M, diag -> pd[]
    float pd[ND];
    #pragma unroll
    for (int i = 0; i < ND; ++i) {
      #pragma unroll
      for (int jj = 0; jj < ND; ++jj) {
        if (jj >= i) {
          float s2 = 0.f;
          #pragma unroll
          for (int k = 0; k < ND; ++k) if (k >= jj) s2 += M[k][i] * M[k][jj];
          if (jj > i) M[i][jj] = s2;
          else pd[i] = s2;
        }
      }
    }

    float mu[ND], q[ND];
    #pragma unroll
    for (int i = 0; i < ND; ++i) mu[i] = means[c * ND + i];
    float muPmu = 0.f;
    #pragma unroll
    for (int i = 0; i < ND; ++i) {
      float a2 = pd[i] * mu[i];
      #pragma unroll
      for (int j = 0; j < ND; ++j) {
        if (j < i) a2 += M[j][i] * mu[j];
        if (j > i) a2 += M[i][j] * mu[j];
      }
      q[i] = a2;
      muPmu += mu[i] * a2;
    }
    float cst = -0.5f * ((float)ND * LOG2PI + logdet + muPmu);

    float wv[64];
    int p = 0;
    #pragma unroll
    for (int i = 0; i < ND; ++i)
      #pragma unroll
      for (int j = 0; j < ND; ++j)
        if (j >= i && !(i == 9 && j == 9))
          wv[p++] = (i == j) ? -0.5f * pd[i] : -M[i][j];
    #pragma unroll
    for (int i = 0; i < ND; ++i) wv[54 + i] = q[i];

    #pragma unroll
    for (int j = 0; j < 32; ++j) {
      float a = wv[2 * j], b = wv[2 * j + 1];
      float ah = __bfloat162float(__float2bfloat16(a));
      float bh = __bfloat162float(__float2bfloat16(b));
      wt[c * 32 + j] = (int)pack_bf16(ah, bh);
      wt[(32 + c) * 32 + j] = (int)pack_bf16(a - ah, b - bh);
    }
    cpack[c] = cst + b_mu[c];        // fold b_c into the per-component const
    cpack[32 + c] = -0.5f * pd[9];   // w99

  } else if (blk == 1) {
    float local = 0.f;
    for (int i = tid; i < NC; i += 256)
      local += fmaf(-0.5f * b_mu[i], b_mu[i], b_ls[i]);
    for (int i = tid; i < NC * NT; i += 256)
      local += fmaf(-0.5f * beta_mu[i], beta_mu[i], beta_ls[i]);
    #pragma unroll
    for (int off = 32; off > 0; off >>= 1) local += __shfl_down(local, off);
    __shared__ float red[4];
    if ((tid & 63) == 0) red[tid >> 6] = local;
    __syncthreads();
    if (tid == 0) acc[0] = (double)(red[0] + red[1] + red[2] + red[3]);

  } else {
    // ---- yz table: {y[k,t], lz[k,t]} ; beta staged in LDS -----------------
    __shared__ float bsh[NC * NT];   // 16 KB
    for (int i = tid; i < NC * NT; i += 256) bsh[i] = beta_mu[i];
    __syncthreads();

    int id = (blk - 2) * 256 + tid;          // id = k*NT + t
    int t = id & (NT - 1);
    float yv = y[id];
    float v[NC];
    float m = -1e30f;
    #pragma unroll
    for (int c = 0; c < NC; ++c) {
      v[c] = fmaf(bsh[c * NT + t], yv, b_mu[c]);
      m = fmaxf(m, v[c]);
    }
    float ssum = 0.f;
    #pragma unroll
    for (int c = 0; c < NC; ++c) ssum += __expf(v[c] - m);
    float lz = m + __logf(ssum);
    ((floatx2*)yz)[id] = (floatx2){yv, lz};

    if (blk == 2) {
      // transposed beta: betaT[t*32+c] = beta_mu[c*128+t]
      for (int i = tid; i < NC * NT; i += 256) {
        int tt2 = i >> 5, cc2 = i & 31;
        betaT[i] = bsh[cc2 * NT + tt2];
      }
    }
  }
}

// ============== MAIN: 4-wave blocks, barrier-free, NO atomics ==============
// r7 loop body verbatim. The ending is the change: previous rounds' 1024
// blocks each did 2 same-address device-scope atomics + threadfence in a
// lockstep finish-burst -> ~100 cyc/block serialized ~= 45 us of tail inside
// this kernel's timestamps (cross-round Dt/Dblocks ~= 105 cyc/block).
// Now: one uncontended plain store per block; finish_kernel does the sum.
__global__ __launch_bounds__(256) __attribute__((amdgpu_waves_per_eu(4, 4)))
void spike_kernel(const float* __restrict__ s,
                  const int* __restrict__ ks,
                  const int* __restrict__ ts,
                  const int* __restrict__ wt,
                  const float* __restrict__ cpack,
                  const float* __restrict__ betaT,
                  const float* __restrict__ yz,
                  double* __restrict__ part) {
  __shared__ int lds[LDS_DW];        // 36 KB: feat (stride 36), then logits
  __shared__ float red[4];

  int tid = threadIdx.x;
  int wv_ = tid >> 6, L = tid & 63;
  int r = L & 15, q = L >> 4;

  // feature index tables: term p = (TJ<0) ? sv[TI] : sv[TI]*sv[TJ]
  static constexpr int TI[64] = {
    0,0,0,0,0,0,0,0,0,0,
    1,1,1,1,1,1,1,1,1,
    2,2,2,2,2,2,2,2,
    3,3,3,3,3,3,3,
    4,4,4,4,4,4,
    5,5,5,5,5,
    6,6,6,6,
    7,7,7,
    8,8,
    0,1,2,3,4,5,6,7,8,9};
  static constexpr int TJ[64] = {
    0,1,2,3,4,5,6,7,8,9,
    1,2,3,4,5,6,7,8,9,
    2,3,4,5,6,7,8,9,
    3,4,5,6,7,8,9,
    4,5,6,7,8,9,
    5,6,7,8,9,
    6,7,8,9,
    7,8,9,
    8,9,
    -1,-1,-1,-1,-1,-1,-1,-1,-1,-1};

  // B-frags (W hi+lo) from global -> registers, once per block
  FragCvt bf[2][2][2];   // [h][nt][kstep]
  #pragma unroll
  for (int h = 0; h < 2; ++h)
    #pragma unroll
    for (int nt = 0; nt < 2; ++nt)
      #pragma unroll
      for (int k2 = 0; k2 < 2; ++k2)
        bf[h][nt][k2].i =
            *(const intx4*)&wt[(h * 32 + nt * 16 + r) * 32 + k2 * 16 + q * 4];

  float lse_sum = 0.f;

  // ---- prefetch chunk 0 (non-temporal: s/ks/ts are stream-once) -----------
  int ci = blockIdx.x;
  floatx4 sA, sB; floatx2 sC; int kk, tt;
  {
    int n = ci * 256 + tid;
    int nc = n < NSPK ? n : (NSPK - 1);
    const float* srow = s + (size_t)nc * ND;
    sA = __builtin_nontemporal_load((const floatx4*)srow);
    sB = __builtin_nontemporal_load((const floatx4*)(srow + 4));
    sC = __builtin_nontemporal_load((const floatx2*)(srow + 8));
    kk = __builtin_nontemporal_load(ks + nc);
    tt = __builtin_nontemporal_load(ts + nc);
  }

  for (; ci < NCHUNK; ci += GRID) {
    int n = ci * 256 + tid;
    float sv[10] = {sA.x, sA.y, sA.z, sA.w, sB.x, sB.y, sB.z, sB.w, sC.x, sC.y};
    float s9sq = sv[9] * sv[9];
    int myt = tt;   // keep this chunk's t before prefetch overwrites

    // ---- issue yz gather (8 B, L2-resident) for THIS chunk ----------------
    floatx2 yzv = ((const floatx2*)yz)[kk * NT + tt];

    // ---- register prefetch of NEXT chunk's s/ks/ts ------------------------
    int cn = ci + GRID;
    if (cn < NCHUNK) {
      int n2 = cn * 256 + tid;
      int nc2 = n2 < NSPK ? n2 : (NSPK - 1);
      const float* srow2 = s + (size_t)nc2 * ND;
      sA = __builtin_nontemporal_load((const floatx4*)srow2);
      sB = __builtin_nontemporal_load((const floatx4*)(srow2 + 4));
      sC = __builtin_nontemporal_load((const floatx2*)(srow2 + 8));
      kk = __builtin_nontemporal_load(ks + nc2);
      tt = __builtin_nontemporal_load(ts + nc2);
    }

    // ---- features fused into bf16 pack -> LDS (own wave slab) -------------
    {
      int rb = tid * FSTR;
      #pragma unroll
      for (int ch = 0; ch < 8; ++ch) {
        float t_[8];
        #pragma unroll
        for (int e = 0; e < 8; ++e) {
          int p = 8 * ch + e;
          t_[e] = (TJ[p] < 0) ? sv[TI[p]] : sv[TI[p]] * sv[TJ[p]];
        }
        intx4 v;
        v.x = (int)pack_bf16(t_[0], t_[1]);
        v.y = (int)pack_bf16(t_[2], t_[3]);
        v.z = (int)pack_bf16(t_[4], t_[5]);
        v.w = (int)pack_bf16(t_[6], t_[7]);
        *(intx4*)&lds[rb + ch * 4] = v;
      }
    }

    // ---- MFMA: D[spike][c] = F x (Whi + Wlo), reads own wave slab ---------
    floatx4 accf[4][2];
    #pragma unroll
    for (int mt = 0; mt < 4; ++mt)
      #pragma unroll
      for (int nt = 0; nt < 2; ++nt)
        accf[mt][nt] = (floatx4){0.f, 0.f, 0.f, 0.f};

    #pragma unroll
    for (int mt = 0; mt < 4; ++mt) {
      #pragma unroll
      for (int k2 = 0; k2 < 2; ++k2) {
        FragCvt a;
        a.i = *(const intx4*)&lds[(wv_ * 64 + mt * 16 + r) * FSTR + k2 * 16 + q * 4];
        #pragma unroll
        for (int nt = 0; nt < 2; ++nt) {
          accf[mt][nt] = __builtin_amdgcn_mfma_f32_16x16x32_bf16(
              a.s, bf[0][nt][k2].s, accf[mt][nt], 0, 0, 0);
          accf[mt][nt] = __builtin_amdgcn_mfma_f32_16x16x32_bf16(
              a.s, bf[1][nt][k2].s, accf[mt][nt], 0, 0, 0);
        }
      }
    }

    // ---- scatter C-frags to LDS logits[spike][c] (own wave slab) ----------
    #pragma unroll
    for (int mt = 0; mt < 4; ++mt)
      #pragma unroll
      for (int nt = 0; nt < 2; ++nt)
        #pragma unroll
        for (int rr = 0; rr < 4; ++rr) {
          int srow_ = wv_ * 64 + mt * 16 + q * 4 + rr;
          lds[srow_ * FSTR + nt * 16 + r] = __float_as_int(accf[mt][nt][rr]);
        }

    // ---- epilogue: lg = FW + cst' + w99*s9^2 + beta[.,t]*y ; LSE - lz -----
    {
      int base = tid * FSTR;
      float lg[32];
      #pragma unroll
      for (int g = 0; g < 8; ++g) {
        intx4 lv = *(const intx4*)&lds[base + g * 4];
        lg[4 * g + 0] = __int_as_float(lv.x);
        lg[4 * g + 1] = __int_as_float(lv.y);
        lg[4 * g + 2] = __int_as_float(lv.z);
        lg[4 * g + 3] = __int_as_float(lv.w);
      }
      const float4* btp = (const float4*)(betaT + myt * NC);  // 128 B, L1-hot
      #pragma unroll
      for (int g = 0; g < 8; ++g) {
        float4 b4 = btp[g];
        lg[4 * g + 0] += fmaf(b4.x, yzv.x, fmaf(cpack[32 + 4*g+0], s9sq, cpack[4*g+0]));
        lg[4 * g + 1] += fmaf(b4.y, yzv.x, fmaf(cpack[32 + 4*g+1], s9sq, cpack[4*g+1]));
        lg[4 * g + 2] += fmaf(b4.z, yzv.x, fmaf(cpack[32 + 4*g+2], s9sq, cpack[4*g+2]));
        lg[4 * g + 3] += fmaf(b4.w, yzv.x, fmaf(cpack[32 + 4*g+3], s9sq, cpack[4*g+3]));
      }

      // max via 5-level tree (exact; cuts 31-deep dependent chain to 5)
      float m16[16];
      #pragma unroll
      for (int c = 0; c < 16; ++c) m16[c] = fmaxf(lg[c], lg[c + 16]);
      float m8[8];
      #pragma unroll
      for (int c = 0; c < 8; ++c) m8[c] = fmaxf(m16[c], m16[c + 8]);
      float m4[4];
      #pragma unroll
      for (int c = 0; c < 4; ++c) m4[c] = fmaxf(m8[c], m8[c + 4]);
      float m = fmaxf(fmaxf(m4[0], m4[1]), fmaxf(m4[2], m4[3]));

      float ss0 = 0.f, ss1 = 0.f, ss2 = 0.f, ss3 = 0.f;
      #pragma unroll
      for (int c = 0; c < 8; ++c) {
        ss0 += __expf(lg[4 * c + 0] - m);
        ss1 += __expf(lg[4 * c + 1] - m);
        ss2 += __expf(lg[4 * c + 2] - m);
        ss3 += __expf(lg[4 * c + 3] - m);
      }
      float ssum = (ss0 + ss1) + (ss2 + ss3);
      if (n < NSPK) lse_sum += m + __logf(ssum) - yzv.y;
    }
  }

  // block reduction -> ONE uncontended plain store per block (no atomics)
  #pragma unroll
  for (int off = 32; off > 0; off >>= 1) lse_sum += __shfl_down(lse_sum, off);
  if ((tid & 63) == 0) red[tid >> 6] = lse_sum;
  __syncthreads();
  if (tid == 0)
    part[blockIdx.x] = (double)(red[0] + red[1] + red[2] + red[3]);
}

// ============================ FINISH =======================================
// Sums the 1024 per-block partials + prep's scalar term. Same-stream kernel
// ordering guarantees visibility of spike's plain stores.
__global__ void finish_kernel(const double* __restrict__ part,
                              const double* __restrict__ acc,
                              float* __restrict__ out) {
  int tid = threadIdx.x;
  double sum = 0.0;
  for (int i = tid; i < GRID; i += 256) sum += part[i];
  #pragma unroll
  for (int off = 32; off > 0; off >>= 1) sum += __shfl_down(sum, off);
  __shared__ double red[4];
  if ((tid & 63) == 0) red[tid >> 6] = sum;
  __syncthreads();
  if (tid == 0)
    out[0] = (float)(acc[0] + red[0] + red[1] + red[2] + red[3]);
}

extern "C" void kernel_launch(void* const* d_in, const int* in_sizes, int n_in,
                              void* d_out, int out_size, void* d_ws, size_t ws_size,
                              hipStream_t stream) {
  const float* s       = (const float*)d_in[0];
  const float* y       = (const float*)d_in[1];
  const int*   ks      = (const int*)d_in[2];
  const int*   ts      = (const int*)d_in[3];
  const float* means   = (const float*)d_in[4];
  const float* covs    = (const float*)d_in[5];
  const float* b_mu    = (const float*)d_in[6];
  const float* b_ls    = (const float*)d_in[7];
  const float* beta_mu = (const float*)d_in[8];
  const float* beta_ls = (const float*)d_in[9];
  float* out = (float*)d_out;

  char* ws = (char*)d_ws;
  double* acc           = (double*)ws;
  float* cpack          = (float*)(ws + 64);
  int* wt               = (int*)(ws + 1024);
  float* betaT          = (float*)(ws + 12288);
  float* yz             = (float*)(ws + 32768);
  double* part          = (double*)(ws + 294912);

  prep_kernel<<<2 + (NK * NT) / 256, 256, 0, stream>>>(
      y, means, covs, b_mu, b_ls, beta_mu, beta_ls, wt, cpack, betaT, yz, acc);
  spike_kernel<<<GRID, 256, 0, stream>>>(
      s, ks, ts, wt, cpack, betaT, yz, part);
  finish_kernel<<<1, 256, 0, stream>>>(part, acc, out);
}